// Round 5
// baseline (901.268 us; speedup 1.0000x reference)
//
#include <hip/hip_runtime.h>

#define NN 20000
#define EE 320000
#define DD 128
#define LL 5
#define EVV 5
#define BNEPS 1e-5f
#define NB 313              // gemm row-blocks: ceil(20000/64)
#define EMB_BLOCKS 2500     // NN*32/256
#define CVT_BLOCKS 160      // 2*5*128*128/4/256
#define CNT_BLOCKS 1250     // EE/256

typedef __attribute__((ext_vector_type(8))) short bf8_t;   // 8 bf16 (4 VGPRs)
typedef __attribute__((ext_vector_type(4))) float f4_t;    // 4 fp32

__device__ inline unsigned short f2bf(float f) {
    union { float f; unsigned u; } v;
    v.f = f;
    unsigned r = v.u + 0x7fffu + ((v.u >> 16) & 1u);  // RTN-even
    return (unsigned short)(r >> 16);
}
__device__ inline float bf2f(unsigned short h) {
    union { unsigned u; float f; } v;
    v.u = ((unsigned)h) << 16;
    return v.f;
}

// BN-affine + optional relu + cross-stitch for one float4 pair (both towers)
__device__ inline void xform4(float4 v1, float4 v2,
                              float4 s1, float4 t1, float4 s2, float4 t2,
                              float c00, float c01, float c10, float c11,
                              int dorelu, float4& n1, float4& n2) {
    float x1, x2, m1, m2;
#define XE(f)                                                    \
    x1 = v1.f * s1.f + t1.f;                                     \
    x2 = v2.f * s2.f + t2.f;                                     \
    x1 = dorelu ? fmaxf(x1, 0.f) : x1;                           \
    x2 = dorelu ? fmaxf(x2, 0.f) : x2;                           \
    m1 = c00 * x1 + c01 * x2;                                    \
    m2 = c10 * m1 + c11 * x2;                                    \
    n1.f = m1;                                                   \
    n2.f = m2;
    XE(x) XE(y) XE(z) XE(w)
#undef XE
}

__device__ inline void acc_relu4(float4& a, float4 v, float4 e) {
    a.x += fmaxf(v.x + e.x, 0.f);
    a.y += fmaxf(v.y + e.y, 0.f);
    a.z += fmaxf(v.z + e.z, 0.f);
    a.w += fmaxf(v.w + e.w, 0.f);
}

// ---------------- prep: embed gather (interleaved) + W->bf16 hi/lo + degree count + identity stt ----------------

__global__ __launch_bounds__(256) void prep_kernel(
    const int* __restrict__ x,
    const float4* __restrict__ e1, const float4* __restrict__ e2,
    float4* __restrict__ yb,
    const float4* __restrict__ Wall,
    ushort4* __restrict__ Wbh, ushort4* __restrict__ Wbl,
    const int* __restrict__ dst, int* __restrict__ deg,
    float* __restrict__ id_stt, float* __restrict__ id_cross) {
    int bid = blockIdx.x;
    int tid = threadIdx.x;
    if (bid < EMB_BLOCKS) {
        int idx = bid * 256 + tid;  // < NN*32 exactly
        int r = idx >> 5, c = idx & 31;
        int v = x[r];
        yb[(size_t)r * 64 + c] = e1[v * 32 + c];
        yb[(size_t)r * 64 + 32 + c] = e2[v * 32 + c];
    } else if (bid < EMB_BLOCKS + CVT_BLOCKS) {
        int i = (bid - EMB_BLOCKS) * 256 + tid;
        float4 w = Wall[i];
        ushort4 oh, ol;
        oh.x = f2bf(w.x); oh.y = f2bf(w.y); oh.z = f2bf(w.z); oh.w = f2bf(w.w);
        ol.x = f2bf(w.x - bf2f(oh.x));
        ol.y = f2bf(w.y - bf2f(oh.y));
        ol.z = f2bf(w.z - bf2f(oh.z));
        ol.w = f2bf(w.w - bf2f(oh.w));
        Wbh[i] = oh;
        Wbl[i] = ol;
    } else if (bid < EMB_BLOCKS + CVT_BLOCKS + CNT_BLOCKS) {
        int e = (bid - EMB_BLOCKS - CVT_BLOCKS) * 256 + tid;  // < EE exactly
        atomicAdd(&deg[dst[e]], 1);
    } else {
        // identity BN scale/shift + identity cross (layer-0 aggregate)
        int a = tid, b = tid + 256;
        id_stt[a] = (a < 128) ? 1.f : 0.f;
        id_stt[b] = (b < 384) ? 1.f : 0.f;
        if (tid == 0) {
            id_cross[0] = 1.f; id_cross[1] = 0.f;
            id_cross[2] = 0.f; id_cross[3] = 1.f;
        }
    }
}

// ---------------- CSR scan (wave-shuffle based) ----------------

__global__ __launch_bounds__(1024) void scan_kernel(const int* __restrict__ deg,
                                                    int* __restrict__ offs,
                                                    int* __restrict__ pos) {
    __shared__ int wsum[16];
    int t = threadIdx.x;
    int lane = t & 63, wv = t >> 6;
    int base = t * 20;
    int loc[20];
    int s = 0;
#pragma unroll
    for (int i = 0; i < 20; i++) {
        int j = base + i;
        int d = (j < NN) ? deg[j] : 0;
        loc[i] = d;
        s += d;
    }
    int incl = s;
#pragma unroll
    for (int o = 1; o < 64; o <<= 1) {
        int v = __shfl_up(incl, o, 64);
        if (lane >= o) incl += v;
    }
    if (lane == 63) wsum[wv] = incl;
    __syncthreads();
    if (t < 16) {
        int v = wsum[t];
        int iv = v;
#pragma unroll
        for (int o = 1; o < 16; o <<= 1) {
            int u = __shfl_up(iv, o, 64);
            if (t >= o) iv += u;
        }
        wsum[t] = iv - v;  // exclusive wave offset
    }
    __syncthreads();
    int run = wsum[wv] + (incl - s);
#pragma unroll
    for (int i = 0; i < 20; i++) {
        int j = base + i;
        if (j < NN) {
            offs[j] = run;
            pos[j] = run;
            run += loc[i];
        }
    }
}

__global__ __launch_bounds__(256) void scatter_kernel(const int* __restrict__ src,
                                                      const int* __restrict__ dst,
                                                      const int* __restrict__ eattr,
                                                      int* __restrict__ pos,
                                                      int2* __restrict__ erec) {
    int e = blockIdx.x * 256 + threadIdx.x;
    if (e < EE) {
        int d = dst[e];
        int p = atomicAdd(&pos[d], 1);
        erec[p] = make_int2(src[e], eattr[e]);
    }
}

// ---------------- fused aggregate: gather y, BN+relu+cross on the fly, emit u bf16 hi/lo ----------------

__global__ __launch_bounds__(256) void aggregate_kernel(
    const float* __restrict__ yb, const float* __restrict__ etab, int layer,
    const int* __restrict__ offs, const int* __restrict__ deg,
    const int2* __restrict__ erec, const float* __restrict__ epsall,
    const float* __restrict__ stt, const float* __restrict__ crossp, int dorelu,
    unsigned short* __restrict__ ubuf, float* __restrict__ stats, int* __restrict__ cnt) {
    int tid = threadIdx.x;
    if (blockIdx.x == 0) {  // zero BN-stat accumulators + last-block counters for this layer
        stats[tid] = 0.f;
        stats[tid + 256] = 0.f;
        if (tid < 2) cnt[tid] = 0;
    }
    int node = blockIdx.x * 4 + (tid >> 6);  // grid 5000*4 == NN exactly
    int lane = tid & 63;
    int half = lane >> 5;       // edge-slot within group (also tower for epilogue)
    int c = lane & 31;          // float4 column
    const float4* y4 = (const float4*)yb;
    const float4* t1v = (const float4*)(etab + (size_t)(0 * LL + layer) * EVV * DD);
    const float4* t2v = (const float4*)(etab + (size_t)(1 * LL + layer) * EVV * DD);
    const float4* st4 = (const float4*)stt;
    float4 s1 = st4[c], t1 = st4[32 + c], s2 = st4[64 + c], t2 = st4[96 + c];
    float c00 = crossp[0], c01 = crossp[1], c10 = crossp[2], c11 = crossp[3];

    int off = offs[node];
    int dg = deg[node];
    float4 a1; a1.x = a1.y = a1.z = a1.w = 0.f;
    float4 a2; a2.x = a2.y = a2.z = a2.w = 0.f;
    int i = 0;
    // main: 8 edges per iteration (4 per half-slot); 16 y-gathers in flight
    for (; i + 8 <= dg; i += 8) {
        int2 r0 = erec[off + i + half];
        int2 r1 = erec[off + i + 2 + half];
        int2 r2 = erec[off + i + 4 + half];
        int2 r3 = erec[off + i + 6 + half];
        float4 v10 = y4[(size_t)r0.x * 64 + c];
        float4 v20 = y4[(size_t)r0.x * 64 + 32 + c];
        float4 v11 = y4[(size_t)r1.x * 64 + c];
        float4 v21 = y4[(size_t)r1.x * 64 + 32 + c];
        float4 v12 = y4[(size_t)r2.x * 64 + c];
        float4 v22 = y4[(size_t)r2.x * 64 + 32 + c];
        float4 v13 = y4[(size_t)r3.x * 64 + c];
        float4 v23 = y4[(size_t)r3.x * 64 + 32 + c];
        float4 e10 = t1v[r0.y * 32 + c];
        float4 e20 = t2v[r0.y * 32 + c];
        float4 e11 = t1v[r1.y * 32 + c];
        float4 e21 = t2v[r1.y * 32 + c];
        float4 e12 = t1v[r2.y * 32 + c];
        float4 e22 = t2v[r2.y * 32 + c];
        float4 e13 = t1v[r3.y * 32 + c];
        float4 e23 = t2v[r3.y * 32 + c];
        float4 n1, n2;
        xform4(v10, v20, s1, t1, s2, t2, c00, c01, c10, c11, dorelu, n1, n2);
        acc_relu4(a1, n1, e10);
        acc_relu4(a2, n2, e20);
        xform4(v11, v21, s1, t1, s2, t2, c00, c01, c10, c11, dorelu, n1, n2);
        acc_relu4(a1, n1, e11);
        acc_relu4(a2, n2, e21);
        xform4(v12, v22, s1, t1, s2, t2, c00, c01, c10, c11, dorelu, n1, n2);
        acc_relu4(a1, n1, e12);
        acc_relu4(a2, n2, e22);
        xform4(v13, v23, s1, t1, s2, t2, c00, c01, c10, c11, dorelu, n1, n2);
        acc_relu4(a1, n1, e13);
        acc_relu4(a2, n2, e23);
    }
    // remainder (<=7 edges), predicated, 2 per iteration
    for (; i < dg; i += 2) {
        int j = i + half;
        bool valid = (j < dg);
        int e = off + (valid ? j : 0);
        int2 r = erec[e];
        float4 v1 = y4[(size_t)r.x * 64 + c];
        float4 v2 = y4[(size_t)r.x * 64 + 32 + c];
        float4 e1 = t1v[r.y * 32 + c];
        float4 e2 = t2v[r.y * 32 + c];
        float4 n1, n2;
        xform4(v1, v2, s1, t1, s2, t2, c00, c01, c10, c11, dorelu, n1, n2);
        if (valid) {
            acc_relu4(a1, n1, e1);
            acc_relu4(a2, n2, e2);
        }
    }
    // combine the two half-wave partials
    a1.x += __shfl_xor(a1.x, 32, 64);
    a1.y += __shfl_xor(a1.y, 32, 64);
    a1.z += __shfl_xor(a1.z, 32, 64);
    a1.w += __shfl_xor(a1.w, 32, 64);
    a2.x += __shfl_xor(a2.x, 32, 64);
    a2.y += __shfl_xor(a2.y, 32, 64);
    a2.z += __shfl_xor(a2.z, 32, 64);
    a2.w += __shfl_xor(a2.w, 32, 64);

    // self term: h_self = xform(y_self); u = (1+eps)*h_self + agg
    float4 vs1 = y4[(size_t)node * 64 + c];
    float4 vs2 = y4[(size_t)node * 64 + 32 + c];
    float4 hn1, hn2;
    xform4(vs1, vs2, s1, t1, s2, t2, c00, c01, c10, c11, dorelu, hn1, hn2);
    float ep = 1.0f + epsall[half * LL + layer];
    float4 hs = half ? hn2 : hn1;
    float4 aa = half ? a2 : a1;
    float4 u;
    u.x = ep * hs.x + aa.x;
    u.y = ep * hs.y + aa.y;
    u.z = ep * hs.z + aa.z;
    u.w = ep * hs.w + aa.w;
    // split bf16: hi + lo
    ushort4 uh, ul;
    uh.x = f2bf(u.x); uh.y = f2bf(u.y); uh.z = f2bf(u.z); uh.w = f2bf(u.w);
    ul.x = f2bf(u.x - bf2f(uh.x));
    ul.y = f2bf(u.y - bf2f(uh.y));
    ul.z = f2bf(u.z - bf2f(uh.z));
    ul.w = f2bf(u.w - bf2f(uh.w));
    // row = 512 bf16 = 128 ushort4: [t0hi(32) | t1hi(32) | t0lo(32) | t1lo(32)]
    ushort4* uo = (ushort4*)ubuf;
    uo[(size_t)node * 128 + half * 32 + c] = uh;
    uo[(size_t)node * 128 + 64 + half * 32 + c] = ul;
}

// ---------------- MFMA GEMM (split-precision): y = u @ W^T + b + fused BN-finalize ----------------

__global__ __launch_bounds__(256) void gemm_mfma_kernel(
    const unsigned short* __restrict__ ubuf,
    const unsigned short* __restrict__ Wbh, const unsigned short* __restrict__ Wbl,
    const float* __restrict__ ball, int layer,
    float* __restrict__ yb,
    float* __restrict__ stats, int* __restrict__ cnt,
    const float* __restrict__ gall, const float* __restrict__ btall,
    float* __restrict__ stt) {
    __shared__ float sP[2][4][DD];  // {sum,sq} x wave x channel
    __shared__ int lastFlag;
    int tid = threadIdx.x;
    int tower = blockIdx.y;
    const bf8_t* Wh8 = (const bf8_t*)(Wbh + (size_t)(tower * LL + layer) * DD * DD);
    const bf8_t* Wl8 = (const bf8_t*)(Wbl + (size_t)(tower * LL + layer) * DD * DD);
    const float* bias = ball + (size_t)(tower * LL + layer) * DD;
    const bf8_t* u8 = (const bf8_t*)ubuf;

    int wave = tid >> 6, lane = tid & 63;
    int quad = lane >> 4, m = lane & 15;
    int row_base = blockIdx.x * 64 + wave * 16;

    f4_t acc[8];
#pragma unroll
    for (int nt = 0; nt < 8; nt++) {
        acc[nt][0] = 0.f; acc[nt][1] = 0.f; acc[nt][2] = 0.f; acc[nt][3] = 0.f;
    }

    // A row stride = 512 bf16 = 64 bf8 units; tower offset 16; lo at +32.
    // Rows past NN read in-ws garbage; their acc regs are never stored.
    int aidx = (row_base + m) * 64 + tower * 16;
#pragma unroll
    for (int kt = 0; kt < 4; kt++) {
        bf8_t ah = u8[aidx + kt * 4 + quad];
        bf8_t al = u8[aidx + 32 + kt * 4 + quad];
#pragma unroll
        for (int nt = 0; nt < 8; nt++) {
            bf8_t bh = Wh8[(nt * 16 + m) * 16 + kt * 4 + quad];
            bf8_t bl = Wl8[(nt * 16 + m) * 16 + kt * 4 + quad];
            acc[nt] = __builtin_amdgcn_mfma_f32_16x16x32_bf16(ah, bh, acc[nt], 0, 0, 0);
            acc[nt] = __builtin_amdgcn_mfma_f32_16x16x32_bf16(al, bh, acc[nt], 0, 0, 0);
            acc[nt] = __builtin_amdgcn_mfma_f32_16x16x32_bf16(ah, bl, acc[nt], 0, 0, 0);
        }
    }

    // Epilogue: D layout col = nt*16 + m, row = quad*4 + reg
#pragma unroll
    for (int nt = 0; nt < 8; nt++) {
        int col = nt * 16 + m;
        float bv = bias[col];
        float s = 0.f, q = 0.f;
#pragma unroll
        for (int r = 0; r < 4; r++) {
            int row = row_base + quad * 4 + r;
            if (row < NN) {
                float v = acc[nt][r] + bv;
                yb[(size_t)row * 256 + tower * DD + col] = v;
                s += v;
                q += v * v;
            }
        }
        s += __shfl_xor(s, 16, 64); s += __shfl_xor(s, 32, 64);
        q += __shfl_xor(q, 16, 64); q += __shfl_xor(q, 32, 64);
        if (quad == 0) {
            sP[0][wave][col] = s;
            sP[1][wave][col] = q;
        }
    }
    __syncthreads();
    int ch = tid & 127, sq = tid >> 7;
    float v = sP[sq][0][ch] + sP[sq][1][ch] + sP[sq][2][ch] + sP[sq][3][ch];
    atomicAdd(&stats[tower * 256 + tid], v);  // tid == sq*128+ch
    __threadfence();
    if (tid == 0) {
        int old = atomicAdd(&cnt[tower], 1);
        lastFlag = (old == NB - 1);
    }
    __syncthreads();
    if (lastFlag) {
        __threadfence();
        if (tid < 128) {
            float sum = __hip_atomic_load(&stats[tower * 256 + tid],
                                          __ATOMIC_RELAXED, __HIP_MEMORY_SCOPE_AGENT);
            float sq2 = __hip_atomic_load(&stats[tower * 256 + 128 + tid],
                                          __ATOMIC_RELAXED, __HIP_MEMORY_SCOPE_AGENT);
            const float inv = 1.0f / (float)NN;
            float mu = sum * inv;
            float var = sq2 * inv - mu * mu;
            float rs = rsqrtf(var + BNEPS);
            float g = gall[(size_t)(tower * LL + layer) * DD + tid];
            float be = btall[(size_t)(tower * LL + layer) * DD + tid];
            float sc = rs * g;
            stt[tower * 256 + tid] = sc;
            stt[tower * 256 + 128 + tid] = be - mu * sc;
        }
    }
}

// ---------------- final epilogue: BN + cross (no relu) from interleaved yb -> d_out ----------------

__global__ __launch_bounds__(256) void bn_final_kernel(
    const float4* __restrict__ y4,
    float4* __restrict__ o1, float4* __restrict__ o2,
    const float* __restrict__ stt, const float* __restrict__ crossp) {
    int idx = blockIdx.x * 256 + threadIdx.x;  // < NN*32 exactly
    int r = idx >> 5, c = idx & 31;
    const float4* st4 = (const float4*)stt;
    float4 s1 = st4[c], t1 = st4[32 + c], s2 = st4[64 + c], t2 = st4[96 + c];
    float c00 = crossp[0], c01 = crossp[1], c10 = crossp[2], c11 = crossp[3];
    float4 v1 = y4[(size_t)r * 64 + c];
    float4 v2 = y4[(size_t)r * 64 + 32 + c];
    float4 n1, n2;
    xform4(v1, v2, s1, t1, s2, t2, c00, c01, c10, c11, 0, n1, n2);
    o1[(size_t)r * 32 + c] = n1;
    o2[(size_t)r * 32 + c] = n2;
}

// ---------------- launcher ----------------

extern "C" void kernel_launch(void* const* d_in, const int* in_sizes, int n_in,
                              void* d_out, int out_size, void* d_ws, size_t ws_size,
                              hipStream_t stream) {
    const int* x = (const int*)d_in[0];
    const int* eidx = (const int*)d_in[1];
    const int* eattr = (const int*)d_in[2];
    const float* emb1 = (const float*)d_in[3];
    const float* emb2 = (const float*)d_in[4];
    const float* etab = (const float*)d_in[5];
    const float* epsv = (const float*)d_in[6];
    const float* Wall = (const float*)d_in[7];
    const float* ball = (const float*)d_in[8];
    const float* gall = (const float*)d_in[9];
    const float* btall = (const float*)d_in[10];
    const float* cross = (const float*)d_in[11];
    float* out = (float*)d_out;

    const size_t ND = (size_t)NN * DD;  // 2,560,000
    char* p = (char*)d_ws;
    float* yb = (float*)p;                     p += (size_t)NN * 256 * 4;  // interleaved y
    unsigned short* ubuf = (unsigned short*)p; p += (size_t)NN * 512 * 2;  // u hi/lo interleaved
    unsigned short* Wbh = (unsigned short*)p;  p += (size_t)2 * LL * DD * DD * 2;
    unsigned short* Wbl = (unsigned short*)p;  p += (size_t)2 * LL * DD * DD * 2;
    int* deg = (int*)p;               p += (size_t)NN * 4;
    int* offs = (int*)p;              p += (size_t)NN * 4;
    int* pos = (int*)p;               p += (size_t)NN * 4;
    int2* erec = (int2*)p;            p += (size_t)EE * 8;
    float* stats = (float*)p;         p += 512 * 4;
    int* cnt = (int*)p;               p += 16 * 4;
    float* stt = (float*)p;           p += 512 * 4;
    float* id_stt = (float*)p;        p += 512 * 4;
    float* id_cross = (float*)p;      p += 4 * 4;

    const int* src = eidx;
    const int* dst = eidx + EE;

    hipMemsetAsync(deg, 0, (size_t)NN * 4, stream);
    prep_kernel<<<EMB_BLOCKS + CVT_BLOCKS + CNT_BLOCKS + 1, 256, 0, stream>>>(
        x, (const float4*)emb1, (const float4*)emb2, (float4*)yb,
        (const float4*)Wall, (ushort4*)Wbh, (ushort4*)Wbl, dst, deg, id_stt, id_cross);
    scan_kernel<<<1, 1024, 0, stream>>>(deg, offs, pos);
    scatter_kernel<<<EE / 256, 256, 0, stream>>>(src, dst, eattr, pos, erec);

    for (int l = 0; l < LL; l++) {
        const float* st_l = (l == 0) ? id_stt : stt;
        const float* cr_l = (l == 0) ? id_cross : (cross + (l - 1) * 4);
        aggregate_kernel<<<NN / 4, 256, 0, stream>>>(
            yb, etab, l, offs, deg, erec, epsv, st_l, cr_l, (l == 0) ? 0 : 1,
            ubuf, stats, cnt);
        dim3 g(NB, 2);
        gemm_mfma_kernel<<<g, 256, 0, stream>>>(ubuf, Wbh, Wbl, ball, l, yb,
                                                stats, cnt, gall, btall, stt);
    }
    bn_final_kernel<<<(NN * 32) / 256, 256, 0, stream>>>(
        (const float4*)yb, (float4*)out, (float4*)(out + ND),
        stt, cross + (LL - 1) * 4);
}

// Round 6
// 576.865 us; speedup vs baseline: 1.5624x; 1.5624x over previous
//
#include <hip/hip_runtime.h>

#define NN 20000
#define EE 320000
#define DD 128
#define LL 5
#define EVV 5
#define BNEPS 1e-5f
#define NB 313              // gemm row-blocks: ceil(20000/64)
#define EMB_BLOCKS 2500     // NN*32/256
#define CVT_BLOCKS 160      // 2*5*128*128/4/256
#define CNT_BLOCKS 1250     // EE/256

typedef __attribute__((ext_vector_type(8))) short bf8_t;   // 8 bf16 (4 VGPRs)
typedef __attribute__((ext_vector_type(4))) float f4_t;    // 4 fp32

__device__ inline unsigned short f2bf(float f) {
    union { float f; unsigned u; } v;
    v.f = f;
    unsigned r = v.u + 0x7fffu + ((v.u >> 16) & 1u);  // RTN-even
    return (unsigned short)(r >> 16);
}
__device__ inline float bf2f(unsigned short h) {
    union { unsigned u; float f; } v;
    v.u = ((unsigned)h) << 16;
    return v.f;
}

// BN-affine + optional relu + cross-stitch for one float4 pair (both towers)
__device__ inline void xform4(float4 v1, float4 v2,
                              float4 s1, float4 t1, float4 s2, float4 t2,
                              float c00, float c01, float c10, float c11,
                              int dorelu, float4& n1, float4& n2) {
    float x1, x2, m1, m2;
#define XE(f)                                                    \
    x1 = v1.f * s1.f + t1.f;                                     \
    x2 = v2.f * s2.f + t2.f;                                     \
    x1 = dorelu ? fmaxf(x1, 0.f) : x1;                           \
    x2 = dorelu ? fmaxf(x2, 0.f) : x2;                           \
    m1 = c00 * x1 + c01 * x2;                                    \
    m2 = c10 * m1 + c11 * x2;                                    \
    n1.f = m1;                                                   \
    n2.f = m2;
    XE(x) XE(y) XE(z) XE(w)
#undef XE
}

__device__ inline void acc_relu4(float4& a, float4 v, float4 e) {
    a.x += fmaxf(v.x + e.x, 0.f);
    a.y += fmaxf(v.y + e.y, 0.f);
    a.z += fmaxf(v.z + e.z, 0.f);
    a.w += fmaxf(v.w + e.w, 0.f);
}

// Compute per-thread BN scale/shift float4s (channels 4c..4c+3, both towers)
// from raw {sum,sumsq} stats of the layer that PRODUCED y (index pl).
__device__ inline void bn_coeffs(const float* __restrict__ statsL,
                                 const float* __restrict__ gall,
                                 const float* __restrict__ btall,
                                 int pl, int c,
                                 float4& s1, float4& t1, float4& s2, float4& t2) {
    const float inv = 1.0f / (float)NN;
    int ch = c * 4;
#define BNC(tw, sv, tv)                                                       \
    {                                                                         \
        const float* gp = gall + (size_t)((tw) * LL + pl) * DD + ch;          \
        const float* bp = btall + (size_t)((tw) * LL + pl) * DD + ch;         \
        float r[4];                                                           \
        _Pragma("unroll") for (int j = 0; j < 4; j++) {                       \
            float sum = statsL[(tw) * 256 + ch + j];                          \
            float sq = statsL[(tw) * 256 + 128 + ch + j];                     \
            float mu = sum * inv;                                             \
            float var = sq * inv - mu * mu;                                   \
            float rs = rsqrtf(var + BNEPS);                                   \
            float sc = rs * gp[j];                                            \
            r[j] = sc;                                                        \
            ((float*)&tv)[j] = bp[j] - mu * sc;                               \
        }                                                                     \
        sv.x = r[0]; sv.y = r[1]; sv.z = r[2]; sv.w = r[3];                   \
    }
    BNC(0, s1, t1)
    BNC(1, s2, t2)
#undef BNC
}

// ---------------- prep: embed gather (interleaved) + W->bf16 hi/lo + degree count + stats zero ----------------

__global__ __launch_bounds__(256) void prep_kernel(
    const int* __restrict__ x,
    const float4* __restrict__ e1, const float4* __restrict__ e2,
    float4* __restrict__ yb,
    const float4* __restrict__ Wall,
    ushort4* __restrict__ Wbh, ushort4* __restrict__ Wbl,
    const int* __restrict__ dst, int* __restrict__ deg,
    float* __restrict__ stats) {
    int bid = blockIdx.x;
    int tid = threadIdx.x;
    if (bid < EMB_BLOCKS) {
        int idx = bid * 256 + tid;  // < NN*32 exactly
        int r = idx >> 5, c = idx & 31;
        int v = x[r];
        yb[(size_t)r * 64 + c] = e1[v * 32 + c];
        yb[(size_t)r * 64 + 32 + c] = e2[v * 32 + c];
    } else if (bid < EMB_BLOCKS + CVT_BLOCKS) {
        int i = (bid - EMB_BLOCKS) * 256 + tid;
        float4 w = Wall[i];
        ushort4 oh, ol;
        oh.x = f2bf(w.x); oh.y = f2bf(w.y); oh.z = f2bf(w.z); oh.w = f2bf(w.w);
        ol.x = f2bf(w.x - bf2f(oh.x));
        ol.y = f2bf(w.y - bf2f(oh.y));
        ol.z = f2bf(w.z - bf2f(oh.z));
        ol.w = f2bf(w.w - bf2f(oh.w));
        Wbh[i] = oh;
        Wbl[i] = ol;
    } else if (bid < EMB_BLOCKS + CVT_BLOCKS + CNT_BLOCKS) {
        int e = (bid - EMB_BLOCKS - CVT_BLOCKS) * 256 + tid;  // < EE exactly
        atomicAdd(&deg[dst[e]], 1);
    } else {
        // zero all layers' raw BN-stat accumulators: 5 * 512 floats
#pragma unroll
        for (int i = 0; i < 10; i++) stats[i * 256 + tid] = 0.f;
    }
}

// ---------------- CSR scan (wave-shuffle based) ----------------

__global__ __launch_bounds__(1024) void scan_kernel(const int* __restrict__ deg,
                                                    int* __restrict__ offs,
                                                    int* __restrict__ pos) {
    __shared__ int wsum[16];
    int t = threadIdx.x;
    int lane = t & 63, wv = t >> 6;
    int base = t * 20;
    int loc[20];
    int s = 0;
#pragma unroll
    for (int i = 0; i < 20; i++) {
        int j = base + i;
        int d = (j < NN) ? deg[j] : 0;
        loc[i] = d;
        s += d;
    }
    int incl = s;
#pragma unroll
    for (int o = 1; o < 64; o <<= 1) {
        int v = __shfl_up(incl, o, 64);
        if (lane >= o) incl += v;
    }
    if (lane == 63) wsum[wv] = incl;
    __syncthreads();
    if (t < 16) {
        int v = wsum[t];
        int iv = v;
#pragma unroll
        for (int o = 1; o < 16; o <<= 1) {
            int u = __shfl_up(iv, o, 64);
            if (t >= o) iv += u;
        }
        wsum[t] = iv - v;  // exclusive wave offset
    }
    __syncthreads();
    int run = wsum[wv] + (incl - s);
#pragma unroll
    for (int i = 0; i < 20; i++) {
        int j = base + i;
        if (j < NN) {
            offs[j] = run;
            pos[j] = run;
            run += loc[i];
        }
    }
}

__global__ __launch_bounds__(256) void scatter_kernel(const int* __restrict__ src,
                                                      const int* __restrict__ dst,
                                                      const int* __restrict__ eattr,
                                                      int* __restrict__ pos,
                                                      int2* __restrict__ erec) {
    int e = blockIdx.x * 256 + threadIdx.x;
    if (e < EE) {
        int d = dst[e];
        int p = atomicAdd(&pos[d], 1);
        erec[p] = make_int2(src[e], eattr[e]);
    }
}

// ---------------- fused aggregate: BN-coeff prologue + gather + BN+relu+cross + emit u bf16 hi/lo ----------------

__global__ __launch_bounds__(256) void aggregate_kernel(
    const float* __restrict__ yb, const float* __restrict__ etab, int layer,
    const int* __restrict__ offs, const int* __restrict__ deg,
    const int2* __restrict__ erec, const float* __restrict__ epsall,
    const float* __restrict__ statsPrev,  // raw stats of layer-1 gemm (unused if layer==0)
    const float* __restrict__ gall, const float* __restrict__ btall,
    const float* __restrict__ crossp, int dobn,
    unsigned short* __restrict__ ubuf) {
    int tid = threadIdx.x;
    int node = blockIdx.x * 4 + (tid >> 6);  // grid 5000*4 == NN exactly
    int lane = tid & 63;
    int half = lane >> 5;       // edge-slot within group (also tower for epilogue)
    int c = lane & 31;          // float4 column
    const float4* y4 = (const float4*)yb;
    const float4* t1v = (const float4*)(etab + (size_t)(0 * LL + layer) * EVV * DD);
    const float4* t2v = (const float4*)(etab + (size_t)(1 * LL + layer) * EVV * DD);

    float4 s1, t1, s2, t2;
    float c00, c01, c10, c11;
    if (dobn) {
        bn_coeffs(statsPrev, gall, btall, layer - 1, c, s1, t1, s2, t2);
        c00 = crossp[0]; c01 = crossp[1]; c10 = crossp[2]; c11 = crossp[3];
    } else {
        s1.x = s1.y = s1.z = s1.w = 1.f;
        s2 = s1;
        t1.x = t1.y = t1.z = t1.w = 0.f;
        t2 = t1;
        c00 = 1.f; c01 = 0.f; c10 = 0.f; c11 = 1.f;
    }
    int dorelu = dobn;  // prev layer always has relu (prev < L-1 whenever layer>=1)

    int off = offs[node];
    int dg = deg[node];
    float4 a1; a1.x = a1.y = a1.z = a1.w = 0.f;
    float4 a2; a2.x = a2.y = a2.z = a2.w = 0.f;
    int i = 0;
    // main: 8 edges per iteration (4 per half-slot); 16 y-gathers in flight
    for (; i + 8 <= dg; i += 8) {
        int2 r0 = erec[off + i + half];
        int2 r1 = erec[off + i + 2 + half];
        int2 r2 = erec[off + i + 4 + half];
        int2 r3 = erec[off + i + 6 + half];
        float4 v10 = y4[(size_t)r0.x * 64 + c];
        float4 v20 = y4[(size_t)r0.x * 64 + 32 + c];
        float4 v11 = y4[(size_t)r1.x * 64 + c];
        float4 v21 = y4[(size_t)r1.x * 64 + 32 + c];
        float4 v12 = y4[(size_t)r2.x * 64 + c];
        float4 v22 = y4[(size_t)r2.x * 64 + 32 + c];
        float4 v13 = y4[(size_t)r3.x * 64 + c];
        float4 v23 = y4[(size_t)r3.x * 64 + 32 + c];
        float4 e10 = t1v[r0.y * 32 + c];
        float4 e20 = t2v[r0.y * 32 + c];
        float4 e11 = t1v[r1.y * 32 + c];
        float4 e21 = t2v[r1.y * 32 + c];
        float4 e12 = t1v[r2.y * 32 + c];
        float4 e22 = t2v[r2.y * 32 + c];
        float4 e13 = t1v[r3.y * 32 + c];
        float4 e23 = t2v[r3.y * 32 + c];
        float4 n1, n2;
        xform4(v10, v20, s1, t1, s2, t2, c00, c01, c10, c11, dorelu, n1, n2);
        acc_relu4(a1, n1, e10);
        acc_relu4(a2, n2, e20);
        xform4(v11, v21, s1, t1, s2, t2, c00, c01, c10, c11, dorelu, n1, n2);
        acc_relu4(a1, n1, e11);
        acc_relu4(a2, n2, e21);
        xform4(v12, v22, s1, t1, s2, t2, c00, c01, c10, c11, dorelu, n1, n2);
        acc_relu4(a1, n1, e12);
        acc_relu4(a2, n2, e22);
        xform4(v13, v23, s1, t1, s2, t2, c00, c01, c10, c11, dorelu, n1, n2);
        acc_relu4(a1, n1, e13);
        acc_relu4(a2, n2, e23);
    }
    // remainder (<=7 edges), predicated, 2 per iteration
    for (; i < dg; i += 2) {
        int j = i + half;
        bool valid = (j < dg);
        int e = off + (valid ? j : 0);
        int2 r = erec[e];
        float4 v1 = y4[(size_t)r.x * 64 + c];
        float4 v2 = y4[(size_t)r.x * 64 + 32 + c];
        float4 e1 = t1v[r.y * 32 + c];
        float4 e2 = t2v[r.y * 32 + c];
        float4 n1, n2;
        xform4(v1, v2, s1, t1, s2, t2, c00, c01, c10, c11, dorelu, n1, n2);
        if (valid) {
            acc_relu4(a1, n1, e1);
            acc_relu4(a2, n2, e2);
        }
    }
    // combine the two half-wave partials
    a1.x += __shfl_xor(a1.x, 32, 64);
    a1.y += __shfl_xor(a1.y, 32, 64);
    a1.z += __shfl_xor(a1.z, 32, 64);
    a1.w += __shfl_xor(a1.w, 32, 64);
    a2.x += __shfl_xor(a2.x, 32, 64);
    a2.y += __shfl_xor(a2.y, 32, 64);
    a2.z += __shfl_xor(a2.z, 32, 64);
    a2.w += __shfl_xor(a2.w, 32, 64);

    // self term: h_self = xform(y_self); u = (1+eps)*h_self + agg
    float4 vs1 = y4[(size_t)node * 64 + c];
    float4 vs2 = y4[(size_t)node * 64 + 32 + c];
    float4 hn1, hn2;
    xform4(vs1, vs2, s1, t1, s2, t2, c00, c01, c10, c11, dorelu, hn1, hn2);
    float ep = 1.0f + epsall[half * LL + layer];
    float4 hs = half ? hn2 : hn1;
    float4 aa = half ? a2 : a1;
    float4 u;
    u.x = ep * hs.x + aa.x;
    u.y = ep * hs.y + aa.y;
    u.z = ep * hs.z + aa.z;
    u.w = ep * hs.w + aa.w;
    // split bf16: hi + lo
    ushort4 uh, ul;
    uh.x = f2bf(u.x); uh.y = f2bf(u.y); uh.z = f2bf(u.z); uh.w = f2bf(u.w);
    ul.x = f2bf(u.x - bf2f(uh.x));
    ul.y = f2bf(u.y - bf2f(uh.y));
    ul.z = f2bf(u.z - bf2f(uh.z));
    ul.w = f2bf(u.w - bf2f(uh.w));
    // row = 512 bf16 = 128 ushort4: [t0hi(32) | t1hi(32) | t0lo(32) | t1lo(32)]
    ushort4* uo = (ushort4*)ubuf;
    uo[(size_t)node * 128 + half * 32 + c] = uh;
    uo[(size_t)node * 128 + 64 + half * 32 + c] = ul;
}

// ---------------- MFMA GEMM (split-precision): y = u @ W^T + b, raw stat atomics (no fence) ----------------

__global__ __launch_bounds__(256) void gemm_mfma_kernel(
    const unsigned short* __restrict__ ubuf,
    const unsigned short* __restrict__ Wbh, const unsigned short* __restrict__ Wbl,
    const float* __restrict__ ball, int layer,
    float* __restrict__ yb,
    float* __restrict__ statsL) {
    __shared__ float sP[2][4][DD];  // {sum,sq} x wave x channel
    int tid = threadIdx.x;
    int tower = blockIdx.y;
    const bf8_t* Wh8 = (const bf8_t*)(Wbh + (size_t)(tower * LL + layer) * DD * DD);
    const bf8_t* Wl8 = (const bf8_t*)(Wbl + (size_t)(tower * LL + layer) * DD * DD);
    const float* bias = ball + (size_t)(tower * LL + layer) * DD;
    const bf8_t* u8 = (const bf8_t*)ubuf;

    int wave = tid >> 6, lane = tid & 63;
    int quad = lane >> 4, m = lane & 15;
    int row_base = blockIdx.x * 64 + wave * 16;

    f4_t acc[8];
#pragma unroll
    for (int nt = 0; nt < 8; nt++) {
        acc[nt][0] = 0.f; acc[nt][1] = 0.f; acc[nt][2] = 0.f; acc[nt][3] = 0.f;
    }

    // A row stride = 512 bf16 = 64 bf8 units; tower offset 16; lo at +32.
    // Rows past NN read in-ws garbage; their acc regs are never stored.
    int aidx = (row_base + m) * 64 + tower * 16;
#pragma unroll
    for (int kt = 0; kt < 4; kt++) {
        bf8_t ah = u8[aidx + kt * 4 + quad];
        bf8_t al = u8[aidx + 32 + kt * 4 + quad];
#pragma unroll
        for (int nt = 0; nt < 8; nt++) {
            bf8_t bh = Wh8[(nt * 16 + m) * 16 + kt * 4 + quad];
            bf8_t bl = Wl8[(nt * 16 + m) * 16 + kt * 4 + quad];
            acc[nt] = __builtin_amdgcn_mfma_f32_16x16x32_bf16(ah, bh, acc[nt], 0, 0, 0);
            acc[nt] = __builtin_amdgcn_mfma_f32_16x16x32_bf16(al, bh, acc[nt], 0, 0, 0);
            acc[nt] = __builtin_amdgcn_mfma_f32_16x16x32_bf16(ah, bl, acc[nt], 0, 0, 0);
        }
    }

    // Epilogue: D layout col = nt*16 + m, row = quad*4 + reg
#pragma unroll
    for (int nt = 0; nt < 8; nt++) {
        int col = nt * 16 + m;
        float bv = bias[col];
        float s = 0.f, q = 0.f;
#pragma unroll
        for (int r = 0; r < 4; r++) {
            int row = row_base + quad * 4 + r;
            if (row < NN) {
                float v = acc[nt][r] + bv;
                yb[(size_t)row * 256 + tower * DD + col] = v;
                s += v;
                q += v * v;
            }
        }
        s += __shfl_xor(s, 16, 64); s += __shfl_xor(s, 32, 64);
        q += __shfl_xor(q, 16, 64); q += __shfl_xor(q, 32, 64);
        if (quad == 0) {
            sP[0][wave][col] = s;
            sP[1][wave][col] = q;
        }
    }
    __syncthreads();
    // tid = sq*128 + ch; one atomicAdd per thread; visibility to the NEXT kernel
    // is guaranteed by the launch boundary (no fence needed).
    int ch = tid & 127, sq = tid >> 7;
    float v = sP[sq][0][ch] + sP[sq][1][ch] + sP[sq][2][ch] + sP[sq][3][ch];
    atomicAdd(&statsL[tower * 256 + tid], v);
}

// ---------------- final epilogue: BN (from raw stats) + cross (no relu) -> d_out ----------------

__global__ __launch_bounds__(256) void bn_final_kernel(
    const float4* __restrict__ y4,
    float4* __restrict__ o1, float4* __restrict__ o2,
    const float* __restrict__ statsL,
    const float* __restrict__ gall, const float* __restrict__ btall,
    const float* __restrict__ crossp) {
    int idx = blockIdx.x * 256 + threadIdx.x;  // < NN*32 exactly
    int r = idx >> 5, c = idx & 31;
    float4 s1, t1, s2, t2;
    bn_coeffs(statsL, gall, btall, LL - 1, c, s1, t1, s2, t2);
    float c00 = crossp[0], c01 = crossp[1], c10 = crossp[2], c11 = crossp[3];
    float4 v1 = y4[(size_t)r * 64 + c];
    float4 v2 = y4[(size_t)r * 64 + 32 + c];
    float4 n1, n2;
    xform4(v1, v2, s1, t1, s2, t2, c00, c01, c10, c11, 0, n1, n2);
    o1[(size_t)r * 32 + c] = n1;
    o2[(size_t)r * 32 + c] = n2;
}

// ---------------- launcher ----------------

extern "C" void kernel_launch(void* const* d_in, const int* in_sizes, int n_in,
                              void* d_out, int out_size, void* d_ws, size_t ws_size,
                              hipStream_t stream) {
    const int* x = (const int*)d_in[0];
    const int* eidx = (const int*)d_in[1];
    const int* eattr = (const int*)d_in[2];
    const float* emb1 = (const float*)d_in[3];
    const float* emb2 = (const float*)d_in[4];
    const float* etab = (const float*)d_in[5];
    const float* epsv = (const float*)d_in[6];
    const float* Wall = (const float*)d_in[7];
    const float* ball = (const float*)d_in[8];
    const float* gall = (const float*)d_in[9];
    const float* btall = (const float*)d_in[10];
    const float* cross = (const float*)d_in[11];
    float* out = (float*)d_out;

    const size_t ND = (size_t)NN * DD;  // 2,560,000
    char* p = (char*)d_ws;
    float* yb = (float*)p;                     p += (size_t)NN * 256 * 4;  // interleaved y
    unsigned short* ubuf = (unsigned short*)p; p += (size_t)NN * 512 * 2;  // u hi/lo interleaved
    unsigned short* Wbh = (unsigned short*)p;  p += (size_t)2 * LL * DD * DD * 2;
    unsigned short* Wbl = (unsigned short*)p;  p += (size_t)2 * LL * DD * DD * 2;
    int* deg = (int*)p;               p += (size_t)NN * 4;
    int* offs = (int*)p;              p += (size_t)NN * 4;
    int* pos = (int*)p;               p += (size_t)NN * 4;
    int2* erec = (int2*)p;            p += (size_t)EE * 8;
    float* stats = (float*)p;         p += (size_t)LL * 512 * 4;  // per-layer raw {sum,sq}

    const int* src = eidx;
    const int* dst = eidx + EE;

    hipMemsetAsync(deg, 0, (size_t)NN * 4, stream);
    prep_kernel<<<EMB_BLOCKS + CVT_BLOCKS + CNT_BLOCKS + 1, 256, 0, stream>>>(
        x, (const float4*)emb1, (const float4*)emb2, (float4*)yb,
        (const float4*)Wall, (ushort4*)Wbh, (ushort4*)Wbl, dst, deg, stats);
    scan_kernel<<<1, 1024, 0, stream>>>(deg, offs, pos);
    scatter_kernel<<<EE / 256, 256, 0, stream>>>(src, dst, eattr, pos, erec);

    for (int l = 0; l < LL; l++) {
        aggregate_kernel<<<NN / 4, 256, 0, stream>>>(
            yb, etab, l, offs, deg, erec, epsv,
            stats + (size_t)(l > 0 ? l - 1 : 0) * 512, gall, btall,
            cross + (l > 0 ? (l - 1) * 4 : 0), (l > 0) ? 1 : 0, ubuf);
        dim3 g(NB, 2);
        gemm_mfma_kernel<<<g, 256, 0, stream>>>(ubuf, Wbh, Wbl, ball, l, yb,
                                                stats + (size_t)l * 512);
    }
    bn_final_kernel<<<(NN * 32) / 256, 256, 0, stream>>>(
        (const float4*)yb, (float4*)out, (float4*)(out + ND),
        stats + (size_t)(LL - 1) * 512, gall, btall, cross + (LL - 1) * 4);
}